// Round 2
// baseline (102.317 us; speedup 1.0000x reference)
//
#include <hip/hip_runtime.h>
#include <stdint.h>

#define BATCH   2048
#define INDIM   512
#define OUTDIM  512
#define SDIM    8
#define KTOT    4096      // 8 slices * 512

typedef __attribute__((ext_vector_type(4))) float  f32x4;
typedef __attribute__((ext_vector_type(8))) __bf16 bf16x8;
typedef __attribute__((ext_vector_type(8))) unsigned short u16x8;

__device__ __forceinline__ unsigned short f2bf(float x) {
  unsigned int u = __float_as_uint(x);
  u += 0x7fffu + ((u >> 16) & 1u);      // round-to-nearest-even
  return (unsigned short)(u >> 16);
}

__device__ __forceinline__ void llds16(const void* g, void* s) {
  __builtin_amdgcn_global_load_lds(
      (__attribute__((address_space(1))) void*)g,
      (__attribute__((address_space(3))) void*)s, 16, 0, 0);
}

__device__ __forceinline__ void mkbasis(float t, float* bs) {
  bs[0] = 1.0f; bs[1] = t; bs[2] = t * t; bs[3] = bs[2] * t;
  const float kn[4] = {0.2f, 0.4f, 0.6f, 0.8f};
#pragma unroll
  for (int c = 0; c < 4; ++c) {
    float d = fmaxf(t - kn[c], 0.0f);
    bs[4 + c] = d * d * d;
  }
}

// ---------------------------------------------------------------------------
// prep:
//   blocks [   0, 512): Bt[n][k] = bf16(W[k*512+n])  (transpose-convert)
//   blocks [ 512,1024): Fbf[b][i] = bf16(inp[b][1+i]); basis table (f32)
//   blocks [1024,2048): BiasP[b][o] = sum_s basis[b][s]*b_wts[s][o]  (ws plane)
// ---------------------------------------------------------------------------
__global__ __launch_bounds__(256) void prep_kernel(
    const float* __restrict__ inp, const float* __restrict__ W,
    const float* __restrict__ bwts, unsigned short* __restrict__ Fbf,
    unsigned short* __restrict__ Btf, float* __restrict__ Bas,
    float* __restrict__ BiasP) {
  const int tid = threadIdx.x;
  const int bx  = blockIdx.x;
  if (bx < 512) {
    // ---- W transpose-convert: 64k x 64n tile ----
    const int kt = bx >> 3, ntile = bx & 7;
    const int k0 = kt * 64, n0 = ntile * 64;
    __shared__ float Ts[64][65];           // [n_local][k_local], padded
#pragma unroll
    for (int p = 0; p < 4; ++p) {
      const int r  = (tid >> 4) + p * 16;  // k-local
      const int c4 = (tid & 15) * 4;       // n-local
      float4 v = *(const float4*)&W[(size_t)(k0 + r) * 512 + n0 + c4];
      Ts[c4 + 0][r] = v.x; Ts[c4 + 1][r] = v.y;
      Ts[c4 + 2][r] = v.z; Ts[c4 + 3][r] = v.w;
    }
    __syncthreads();
    const int nl  = tid >> 2;              // 0..63
    const int kcc = (tid & 3) * 16;        // 0,16,32,48
    u16x8 o0, o1;
#pragma unroll
    for (int q = 0; q < 8; ++q) {
      o0[q] = f2bf(Ts[nl][kcc + q]);
      o1[q] = f2bf(Ts[nl][kcc + 8 + q]);
    }
    unsigned short* dst = Btf + (size_t)(n0 + nl) * KTOT + k0 + kcc;
    *(u16x8*)dst = o0;
    *(u16x8*)(dst + 8) = o1;
  } else if (bx < 1024) {
    // ---- feature convert (4 rows per block) + basis table ----
    const int b0   = (bx - 512) * 4;
    const int b    = b0 + (tid >> 6);
    const int i0   = (tid & 63) * 8;
    const float* row = inp + (size_t)b * (INDIM + 1);
    u16x8 o;
#pragma unroll
    for (int q = 0; q < 8; ++q) o[q] = f2bf(row[1 + i0 + q]);
    *(u16x8*)(Fbf + (size_t)b * INDIM + i0) = o;
    if (tid < 4) {
      const int bb = b0 + tid;
      float t = inp[(size_t)bb * (INDIM + 1)];
      float bs[8]; mkbasis(t, bs);
      f32x4 lo = {bs[0], bs[1], bs[2], bs[3]};
      f32x4 hi = {bs[4], bs[5], bs[6], bs[7]};
      *(f32x4*)(Bas + (size_t)bb * 8)     = lo;
      *(f32x4*)(Bas + (size_t)bb * 8 + 4) = hi;
    }
  } else {
    // ---- bias plane: BiasP = basis @ b_wts (2 rows per block) ----
    const int bb = (bx - 1024) * 2 + (tid >> 7);
    const int o0 = (tid & 127) * 4;
    float t = inp[(size_t)bb * (INDIM + 1)];
    float bs[8]; mkbasis(t, bs);
    float4 a = make_float4(0.f, 0.f, 0.f, 0.f);
#pragma unroll
    for (int s = 0; s < 8; ++s) {
      float4 wv = *(const float4*)&bwts[s * OUTDIM + o0];
      a.x += bs[s] * wv.x; a.y += bs[s] * wv.y;
      a.z += bs[s] * wv.z; a.w += bs[s] * wv.w;
    }
    *(float4*)&BiasP[(size_t)bb * OUTDIM + o0] = a;
  }
}

// ---------------------------------------------------------------------------
// GEMM: out = BiasP + sum_s basis[:,s] * (F(2048x512) @ Wk[s](512x512))
// SPLITK=1: grid 256 (= 32 m-tiles x 8 n-tiles), 64x64 tile, full K=4096.
// A (64x512) staged ONCE in LDS, reused across all 8 slices. B double-buffered
// (2x 64x64), m230 2-phase: stage(next) -> compute(cur) -> one __syncthreads.
// Zero atomics; pure stores in epilogue. Fragment/swizzle math identical to
// the verified round-1 kernel (XOR chunk^(row&7) on global source, ds_read
// side applies the same involution).
// ---------------------------------------------------------------------------
__global__ __launch_bounds__(256, 2) void gemm_kernel(
    const unsigned short* __restrict__ Fbf,
    const unsigned short* __restrict__ Btf,
    const float* __restrict__ Bas,
    const float* __restrict__ BiasP,
    float* __restrict__ out) {
  const int tid  = threadIdx.x;
  const int tile = blockIdx.x;           // 256 blocks
  const int nt = tile & 7, mt = tile >> 3;
  const int m0 = mt * 64, n0 = nt * 64;
  const int l = tid & 63, w = tid >> 6;
  const int wm = w >> 1, wn = w & 1;
  const int quad = l >> 4, lr = l & 15;

  __shared__ __align__(16) unsigned short Af[64 * 512];      // 64 KB, full-K A
  __shared__ __align__(16) unsigned short Bs[2][64 * 64];    // 2 x 8 KB

  f32x4 m00 = {}, m01 = {}, m10 = {}, m11 = {};

  // ---- A full-tile stage: 16 rounds, 4 rows x 64 chunks per round ----
  // thread -> (row = rd*4 + tid>>6, chunk pc64 = tid&63); LDS dest linear
  // (rd*4096B + tid*16B); global source chunk = pc64 ^ (row&7).
  {
    const int rsub = tid >> 6;           // 0..3
    const int pc64 = tid & 63;
#pragma unroll
    for (int rd = 0; rd < 16; ++rd) {
      const int row  = rd * 4 + rsub;
      const int lc64 = pc64 ^ (row & 7);
      llds16(Fbf + (size_t)(m0 + row) * INDIM + lc64 * 8,
             &Af[(size_t)rd * 2048 + tid * 8]);
    }
  }

  // ---- B staging map (identical to round-1): row sr, chunk pc, src chunk
  // lc = pc ^ (sr&7); LDS dest = tid*16B (wave-uniform + lane*16). ----
  const int sr = tid >> 3, pc = tid & 7;
  const int lc = pc ^ (sr & 7);
  const unsigned short* Bg = Btf + (size_t)(n0 + sr) * KTOT + lc * 8;

  // fragment read offsets: logical chunk q of row r lives at q ^ (r&7)
  const int sx  = lr & 7;
  const int arA = (wm * 32 + lr) * 512;        // A rows are 512 wide now
  const int br  = (wn * 32 + lr) * 64;
  const int cB0 = ((0 + quad) ^ sx) * 8;
  const int cB1 = ((4 + quad) ^ sx) * 8;

  // prologue: stage B tile 0
  llds16(Bg,              &Bs[0][tid * 8]);
  llds16(Bg + 32 * KTOT,  &Bs[0][tid * 8 + 32 * 64]);
  __syncthreads();

  const float* bp = Bas + (size_t)(m0 + wm * 32 + quad * 4) * 8;

  for (int s = 0; s < 8; ++s) {
    f32x4 p00 = {}, p01 = {}, p10 = {}, p11 = {};
#pragma unroll
    for (int ib = 0; ib < 8; ++ib) {
      const int t   = s * 8 + ib;
      const int cur = t & 1;
      if (t < 63) {
        const unsigned short* Bn = Bg + (size_t)(t + 1) * 64;
        llds16(Bn,             &Bs[cur ^ 1][tid * 8]);
        llds16(Bn + 32 * KTOT, &Bs[cur ^ 1][tid * 8 + 32 * 64]);
      }
      // A chunks for this K-step: logical ib*8 + quad (+4); XOR hits low 3 bits
      const int cA0 = ib * 64 + ((0 + quad) ^ sx) * 8;
      const int cA1 = ib * 64 + ((4 + quad) ^ sx) * 8;

      bf16x8 a00 = *(const bf16x8*)&Af[arA + cA0];
      bf16x8 a10 = *(const bf16x8*)&Af[arA + 16 * 512 + cA0];
      bf16x8 a01 = *(const bf16x8*)&Af[arA + cA1];
      bf16x8 a11 = *(const bf16x8*)&Af[arA + 16 * 512 + cA1];
      bf16x8 b00 = *(const bf16x8*)&Bs[cur][br + cB0];
      bf16x8 b10 = *(const bf16x8*)&Bs[cur][br + 1024 + cB0];
      bf16x8 b01 = *(const bf16x8*)&Bs[cur][br + cB1];
      bf16x8 b11 = *(const bf16x8*)&Bs[cur][br + 1024 + cB1];

      p00 = __builtin_amdgcn_mfma_f32_16x16x32_bf16(a00, b00, p00, 0, 0, 0);
      p01 = __builtin_amdgcn_mfma_f32_16x16x32_bf16(a00, b10, p01, 0, 0, 0);
      p10 = __builtin_amdgcn_mfma_f32_16x16x32_bf16(a10, b00, p10, 0, 0, 0);
      p11 = __builtin_amdgcn_mfma_f32_16x16x32_bf16(a10, b10, p11, 0, 0, 0);
      p00 = __builtin_amdgcn_mfma_f32_16x16x32_bf16(a01, b01, p00, 0, 0, 0);
      p01 = __builtin_amdgcn_mfma_f32_16x16x32_bf16(a01, b11, p01, 0, 0, 0);
      p10 = __builtin_amdgcn_mfma_f32_16x16x32_bf16(a11, b01, p10, 0, 0, 0);
      p11 = __builtin_amdgcn_mfma_f32_16x16x32_bf16(a11, b11, p11, 0, 0, 0);

      __syncthreads();   // drains llds for next buffer; fences cur-buf reuse
    }
    // scale this s-slice's partial by basis[row][s] (f32, exact)
#pragma unroll
    for (int r = 0; r < 4; ++r) {
      const float f0 = bp[r * 8 + s];          // rows quad*4+r
      const float f1 = bp[(16 + r) * 8 + s];   // rows quad*4+r+16
      m00[r] += p00[r] * f0; m01[r] += p01[r] * f0;
      m10[r] += p10[r] * f1; m11[r] += p11[r] * f1;
    }
  }

  // epilogue: pure stores, bias plane added (no atomics, no memset needed)
  const int col = n0 + wn * 32 + lr;
  const int row = m0 + wm * 32 + quad * 4;
  const float* bsrc = BiasP + (size_t)row * OUTDIM + col;
  float* o = out + (size_t)row * OUTDIM + col;
#pragma unroll
  for (int r = 0; r < 4; ++r) {
    o[(size_t)r * OUTDIM]             = m00[r] + bsrc[(size_t)r * OUTDIM];
    o[(size_t)r * OUTDIM + 16]        = m01[r] + bsrc[(size_t)r * OUTDIM + 16];
    o[(size_t)(16 + r) * OUTDIM]      = m10[r] + bsrc[(size_t)(16 + r) * OUTDIM];
    o[(size_t)(16 + r) * OUTDIM + 16] = m11[r] + bsrc[(size_t)(16 + r) * OUTDIM + 16];
  }
}

extern "C" void kernel_launch(void* const* d_in, const int* in_sizes, int n_in,
                              void* d_out, int out_size, void* d_ws, size_t ws_size,
                              hipStream_t stream) {
  const float* inp  = (const float*)d_in[0];   // (2048, 513)
  const float* W    = (const float*)d_in[1];   // (8, 262144) == (4096, 512) row-major
  const float* bwts = (const float*)d_in[2];   // (8, 512)
  float* out = (float*)d_out;

  unsigned short* Fbf = (unsigned short*)d_ws;                  // 2 MB
  unsigned short* Btf = Fbf + (size_t)BATCH * INDIM;            // 4 MB
  float*          Bas = (float*)(Btf + (size_t)OUTDIM * KTOT);  // 64 KB
  float*          BiasP = Bas + (size_t)BATCH * SDIM;           // 4 MB

  prep_kernel<<<2048, 256, 0, stream>>>(inp, W, bwts, Fbf, Btf, Bas, BiasP);
  gemm_kernel<<<(BATCH / 64) * (OUTDIM / 64), 256, 0, stream>>>(Fbf, Btf, Bas, BiasP, out);
}